// Round 6
// baseline (2439.307 us; speedup 1.0000x reference)
//
#include <hip/hip_runtime.h>
#include <hip/hip_bf16.h>

#define SEQ 4096
#define HID 2048
#define HK_ 16
#define HV_ 32
#define KEY_DIM 2048
#define VALUE_DIM 4096
#define CONV_DIM 8192
#define NQKVZ 12288

typedef unsigned short ushort_t;
typedef short bf16x8 __attribute__((ext_vector_type(8)));
typedef float f32x4 __attribute__((ext_vector_type(4)));
typedef float f32x2 __attribute__((ext_vector_type(2)));

__device__ __forceinline__ float bf2f(ushort_t h) {
    union { unsigned int u; float f; } x; x.u = ((unsigned int)h) << 16; return x.f;
}
__device__ __forceinline__ void cvt8(uint4 v, float* f) {
    unsigned int w[4] = {v.x, v.y, v.z, v.w};
#pragma unroll
    for (int i = 0; i < 4; i++) {
        union { unsigned int u; float f; } lo, hi;
        lo.u = w[i] << 16; hi.u = w[i] & 0xffff0000u;
        f[2 * i] = lo.f; f[2 * i + 1] = hi.f;
    }
}
// uint2 of 4 bf16 -> 2x f32x2 (lo,hi pairs), packed-math friendly
__device__ __forceinline__ void cvt4v2(uint2 v, f32x2* f) {
    unsigned int w[2] = {v.x, v.y};
#pragma unroll
    for (int i = 0; i < 2; i++) {
        union { unsigned int u; float f; } lo, hi;
        lo.u = w[i] << 16; hi.u = w[i] & 0xffff0000u;
        f[i] = (f32x2){lo.f, hi.f};
    }
}
__device__ __forceinline__ ushort_t f2bf(float f) {
    union { float f; unsigned int u; } x; x.f = f;
    unsigned int u = x.u;
    u += 0x7fffu + ((u >> 16) & 1u);   // round-to-nearest-even
    return (ushort_t)(u >> 16);
}

// async global->LDS, 16B per lane. LDS dest is wave-uniform base + lane*16.
__device__ __forceinline__ void gload_lds16(const void* g, void* l) {
    __builtin_amdgcn_global_load_lds(
        (const __attribute__((address_space(1))) void*)g,
        (__attribute__((address_space(3))) void*)l, 16, 0, 0);
}

// DPP butterfly add within a 16-lane row (VALU-latency cross-lane).
template <int CTRL>
__device__ __forceinline__ float dpp_add(float x) {
    union { float f; int i; } a, b;
    a.f = x;
    b.i = __builtin_amdgcn_update_dpp(0, a.i, CTRL, 0xF, 0xF, true);
    return a.f + b.f;
}
// full 16-lane sum, result in all 16 lanes of the row
__device__ __forceinline__ float red16(float x) {
    x = dpp_add<0xB1>(x);   // quad_perm [1,0,3,2]  : xor 1
    x = dpp_add<0x4E>(x);   // quad_perm [2,3,0,1]  : xor 2
    x = dpp_add<0x141>(x);  // row_half_mirror      : xor 4 (after quad stages)
    x = dpp_add<0x140>(x);  // row_mirror           : xor 8
    return x;
}
// full 32-lane sum: 4 DPP stages + ds_swizzle xor16 (BitMode 0x401F, ISA doc)
__device__ __forceinline__ float red32(float x) {
    x = red16(x);
    union { float f; int i; } a, b;
    a.f = x;
    b.i = __builtin_amdgcn_ds_swizzle(a.i, 0x401F);   // lane ^ 16 within 32-group
    return a.f + b.f;
}

// ---------------------------------------------------------------------------
// f32 -> bf16 flat copy (n divisible by 2048). 8 elems/thread.
// ---------------------------------------------------------------------------
__global__ void k_cvt(const float* __restrict__ src, ushort_t* __restrict__ dst)
{
    size_t i = ((size_t)blockIdx.x * 256 + threadIdx.x) * 8;
    float4 a = *(const float4*)&src[i];
    float4 b = *(const float4*)&src[i + 4];
    ushort_t u[8];
    u[0]=f2bf(a.x); u[1]=f2bf(a.y); u[2]=f2bf(a.z); u[3]=f2bf(a.w);
    u[4]=f2bf(b.x); u[5]=f2bf(b.y); u[6]=f2bf(b.z); u[7]=f2bf(b.w);
    *(uint4*)&dst[i] = *(uint4*)u;
}

// ---------------------------------------------------------------------------
// Transpose f32 [R][C] -> bf16 [C][R]. 64x64 tiles via LDS. grid (C/64, R/64).
// ---------------------------------------------------------------------------
__global__ __launch_bounds__(256) void k_transpose(const float* __restrict__ src,
                                                   ushort_t* __restrict__ dst,
                                                   int R, int C)
{
    __shared__ float tile[64][65];
    int c0 = blockIdx.x * 64, r0 = blockIdx.y * 64;
    int t = threadIdx.x;
    int tr = t >> 4, tc = (t & 15) * 4;
#pragma unroll
    for (int r = 0; r < 4; r++) {
        float4 v = *(const float4*)&src[(size_t)(r0 + tr + r * 16) * C + c0 + tc];
        tile[tr + r * 16][tc + 0] = v.x;
        tile[tr + r * 16][tc + 1] = v.y;
        tile[tr + r * 16][tc + 2] = v.z;
        tile[tr + r * 16][tc + 3] = v.w;
    }
    __syncthreads();
#pragma unroll
    for (int r = 0; r < 4; r++) {
        int n = c0 + tr + r * 16;           // dst row (src col)
        ushort_t u[4];
#pragma unroll
        for (int i = 0; i < 4; i++) u[i] = f2bf(tile[tc + i][tr + r * 16]);
        *(uint2*)&dst[(size_t)n * R + r0 + tc] = *(uint2*)u;
    }
}

// ---------------------------------------------------------------------------
// ba = hidden @ W_ba (2048x64), f32 in, fused g/beta transform.
// Writes interleaved float2 gb[t*HV_+hv] = (exp(g), beta).
// ---------------------------------------------------------------------------
__global__ void k_ba(const float* __restrict__ A, const float* __restrict__ B,
                     const float* __restrict__ A_log, const float* __restrict__ dt_bias,
                     float* __restrict__ gbf)
{
    __shared__ float As[16][132];
    __shared__ float Bs[16][68];
    int tid = threadIdx.x;
    int m0 = blockIdx.x * 128;
    int tx = tid & 15, ty = tid >> 4;
    int arow = tid >> 2, akq = tid & 3;
    int brow = tid >> 4, bc4 = tid & 15;
    float acc[8][4];
#pragma unroll
    for (int i = 0; i < 8; i++)
#pragma unroll
        for (int j = 0; j < 4; j++) acc[i][j] = 0.f;

    for (int k0 = 0; k0 < HID; k0 += 16) {
        float4 a0 = *(const float4*)&A[(size_t)(m0 + arow) * HID + k0 + akq * 4];
        float4 a1 = *(const float4*)&A[(size_t)(m0 + arow + 64) * HID + k0 + akq * 4];
        float4 b0 = *(const float4*)&B[(size_t)(k0 + brow) * 64 + bc4 * 4];
        __syncthreads();
        As[akq * 4 + 0][arow] = a0.x; As[akq * 4 + 1][arow] = a0.y;
        As[akq * 4 + 2][arow] = a0.z; As[akq * 4 + 3][arow] = a0.w;
        As[akq * 4 + 0][arow + 64] = a1.x; As[akq * 4 + 1][arow + 64] = a1.y;
        As[akq * 4 + 2][arow + 64] = a1.z; As[akq * 4 + 3][arow + 64] = a1.w;
        *(float4*)&Bs[brow][bc4 * 4] = b0;
        __syncthreads();
#pragma unroll
        for (int kk = 0; kk < 16; kk++) {
            float xa[8], yb[4];
            *(float4*)&xa[0] = *(const float4*)&As[kk][ty * 8];
            *(float4*)&xa[4] = *(const float4*)&As[kk][ty * 8 + 4];
            *(float4*)&yb[0] = *(const float4*)&Bs[kk][tx * 4];
#pragma unroll
            for (int i = 0; i < 8; i++)
#pragma unroll
                for (int j = 0; j < 4; j++) acc[i][j] += xa[i] * yb[j];
        }
    }
#pragma unroll
    for (int i = 0; i < 8; i++) {
        int t = m0 + ty * 8 + i;
#pragma unroll
        for (int j = 0; j < 4; j++) {
            int c = tx * 4 + j;
            int hk = c >> 2, rr = c & 3;
            float val = acc[i][j];
            if (rr < 2) {
                int hv = hk * 2 + rr;
                gbf[(t * HV_ + hv) * 2 + 1] = 1.f / (1.f + expf(-val));
            } else {
                int hv = hk * 2 + (rr - 2);
                float v2 = val + dt_bias[hv];
                float sp = (v2 > 20.f) ? v2 : log1pf(expf(v2));
                float g = -expf(A_log[hv]) * sp;
                gbf[(t * HV_ + hv) * 2 + 0] = expf(g);
            }
        }
    }
}

// ---------------------------------------------------------------------------
// MFMA GEMM (m97 structure): global_load_lds width-16 staging, linear LDS.
// qkvz = hs_bf16 [4096][2048] @ WqkvzT_bf16 [12288][2048]^T. grid (96, 32).
// ---------------------------------------------------------------------------
__global__ __launch_bounds__(256) void k_gemm_qkvz(const ushort_t* __restrict__ Ab,
                                                   const ushort_t* __restrict__ Bt,
                                                   ushort_t* __restrict__ preact,
                                                   ushort_t* __restrict__ zb)
{
    __shared__ ushort_t As[128][32];
    __shared__ ushort_t Bs[128][32];
    int tid = threadIdx.x;
    int m0 = blockIdx.y * 128, n0 = blockIdx.x * 128;
    int lane = tid & 63, wave = tid >> 6;
    int wm = (wave >> 1) * 64, wn = (wave & 1) * 64;
    int quad = lane >> 4, l16 = lane & 15;

    int srow = ((wave & 1) << 6) + (lane >> 2);
    int scol = (lane & 3) << 3;
    const ushort_t* gsrc = (wave < 2)
        ? &Ab[(size_t)(m0 + srow) * HID + scol]
        : &Bt[(size_t)(n0 + srow) * HID + scol];
    ushort_t* lbase = ((wave < 2) ? &As[0][0] : &Bs[0][0]) + ((wave & 1) << 11);

    f32x4 acc[4][4];
#pragma unroll
    for (int i = 0; i < 4; i++)
#pragma unroll
        for (int j = 0; j < 4; j++) acc[i][j] = (f32x4){0.f, 0.f, 0.f, 0.f};

    for (int k0 = 0; k0 < HID; k0 += 32) {
#pragma unroll
        for (int i = 0; i < 4; i++)
            gload_lds16(gsrc + k0 + (size_t)i * 16 * HID, lbase + i * 512);
        __syncthreads();
        bf16x8 af[4], bfr[4];
#pragma unroll
        for (int i = 0; i < 4; i++) af[i]  = *(bf16x8*)&As[wm + i * 16 + l16][quad * 8];
#pragma unroll
        for (int j = 0; j < 4; j++) bfr[j] = *(bf16x8*)&Bs[wn + j * 16 + l16][quad * 8];
#pragma unroll
        for (int i = 0; i < 4; i++)
#pragma unroll
            for (int j = 0; j < 4; j++)
                acc[i][j] = __builtin_amdgcn_mfma_f32_16x16x32_bf16(af[i], bfr[j], acc[i][j], 0, 0, 0);
        __syncthreads();
    }
    int hk = n0 / 768, r = n0 % 768;
    ushort_t* dst; int ldd;
    if (r < 128)      { dst = preact + hk * 128;                    ldd = CONV_DIM; }
    else if (r < 256) { dst = preact + 2048 + hk * 128;             ldd = CONV_DIM; }
    else if (r < 512) { dst = preact + 4096 + hk * 256 + (r - 256); ldd = CONV_DIM; }
    else              { dst = zb + hk * 256 + (r - 512);            ldd = VALUE_DIM; }
#pragma unroll
    for (int i = 0; i < 4; i++)
#pragma unroll
        for (int j = 0; j < 4; j++)
#pragma unroll
            for (int rg = 0; rg < 4; rg++) {
                int m = m0 + wm + i * 16 + quad * 4 + rg;
                int n = wn + j * 16 + l16;
                dst[(size_t)m * ldd + n] = f2bf(acc[i][j][rg]);
            }
}

// ---------------------------------------------------------------------------
// MFMA GEMM (m97 structure): out = core_bf16 [4096][4096] @ WoutT [2048][4096]^T.
// grid (16, 32).
// ---------------------------------------------------------------------------
__global__ __launch_bounds__(256) void k_gemm_out(const ushort_t* __restrict__ Ab,
                                                  const ushort_t* __restrict__ Bt,
                                                  float* __restrict__ C)
{
    __shared__ ushort_t As[128][32];
    __shared__ ushort_t Bs[128][32];
    int tid = threadIdx.x;
    int m0 = blockIdx.y * 128, n0 = blockIdx.x * 128;
    int lane = tid & 63, wave = tid >> 6;
    int wm = (wave >> 1) * 64, wn = (wave & 1) * 64;
    int quad = lane >> 4, l16 = lane & 15;

    int srow = ((wave & 1) << 6) + (lane >> 2);
    int scol = (lane & 3) << 3;
    const ushort_t* gsrc = (wave < 2)
        ? &Ab[(size_t)(m0 + srow) * VALUE_DIM + scol]
        : &Bt[(size_t)(n0 + srow) * VALUE_DIM + scol];
    ushort_t* lbase = ((wave < 2) ? &As[0][0] : &Bs[0][0]) + ((wave & 1) << 11);

    f32x4 acc[4][4];
#pragma unroll
    for (int i = 0; i < 4; i++)
#pragma unroll
        for (int j = 0; j < 4; j++) acc[i][j] = (f32x4){0.f, 0.f, 0.f, 0.f};

    for (int k0 = 0; k0 < VALUE_DIM; k0 += 32) {
#pragma unroll
        for (int i = 0; i < 4; i++)
            gload_lds16(gsrc + k0 + (size_t)i * 16 * VALUE_DIM, lbase + i * 512);
        __syncthreads();
        bf16x8 af[4], bfr[4];
#pragma unroll
        for (int i = 0; i < 4; i++) af[i]  = *(bf16x8*)&As[wm + i * 16 + l16][quad * 8];
#pragma unroll
        for (int j = 0; j < 4; j++) bfr[j] = *(bf16x8*)&Bs[wn + j * 16 + l16][quad * 8];
#pragma unroll
        for (int i = 0; i < 4; i++)
#pragma unroll
            for (int j = 0; j < 4; j++)
                acc[i][j] = __builtin_amdgcn_mfma_f32_16x16x32_bf16(af[i], bfr[j], acc[i][j], 0, 0, 0);
        __syncthreads();
    }
#pragma unroll
    for (int i = 0; i < 4; i++)
#pragma unroll
        for (int j = 0; j < 4; j++)
#pragma unroll
            for (int rg = 0; rg < 4; rg++) {
                int m = m0 + wm + i * 16 + quad * 4 + rg;
                int n = n0 + wn + j * 16 + l16;
                C[(size_t)m * HID + n] = acc[i][j][rg];
            }
}

// ---------------------------------------------------------------------------
// Causal conv(K=4) + SiLU; l2norm for q/k heads. Vectorized: 8 ch/thread.
// grid (4, SEQ/4), block 256. block.x 0: q, 1: k, 2-3: v.
// ---------------------------------------------------------------------------
__global__ __launch_bounds__(256) void k_conv(const ushort_t* __restrict__ pre,
                                              const float* __restrict__ cw,
                                              ushort_t* __restrict__ qn,
                                              ushort_t* __restrict__ kn,
                                              ushort_t* __restrict__ vv)
{
    int tid = threadIdx.x;
    int c = blockIdx.x * 2048 + tid * 8;
    int t0 = blockIdx.y * 4;
    float w[8][4];
#pragma unroll
    for (int j = 0; j < 8; j++)
        *(float4*)w[j] = *(const float4*)&cw[(size_t)(c + j) * 4];
    float p[7][8];
#pragma unroll
    for (int i = 0; i < 7; i++) {
        int tt = t0 + i - 3;
        if (tt >= 0) {
            uint4 v = *(const uint4*)&pre[(size_t)tt * CONV_DIM + c];
            cvt8(v, p[i]);
        } else {
#pragma unroll
            for (int j = 0; j < 8; j++) p[i][j] = 0.f;
        }
    }
    float x[4][8];
#pragma unroll
    for (int u = 0; u < 4; u++)
#pragma unroll
        for (int j = 0; j < 8; j++) {
            float a = p[u][j] * w[j][0] + p[u + 1][j] * w[j][1]
                    + p[u + 2][j] * w[j][2] + p[u + 3][j] * w[j][3];
            x[u][j] = a / (1.f + expf(-a));
        }
    if (blockIdx.x < 2) {
        bool isq = (blockIdx.x == 0);
        float headscale = isq ? 0.08838834764831845f : 1.f;
        ushort_t* dst = isq ? qn : kn;
        int cc = isq ? c : (c - KEY_DIM);
#pragma unroll
        for (int u = 0; u < 4; u++) {
            float ss = 0.f;
#pragma unroll
            for (int j = 0; j < 8; j++) ss += x[u][j] * x[u][j];
            ss = red16(ss);                      // head = 128 ch = 16 lanes
            float mul = headscale / sqrtf(ss + 1e-6f);
            ushort_t o[8];
#pragma unroll
            for (int j = 0; j < 8; j++) o[j] = f2bf(x[u][j] * mul);
            *(uint4*)&dst[(size_t)(t0 + u) * KEY_DIM + cc] = *(uint4*)o;
        }
    } else {
        int cc = c - 2 * KEY_DIM;
#pragma unroll
        for (int u = 0; u < 4; u++) {
            ushort_t o[8];
#pragma unroll
            for (int j = 0; j < 8; j++) o[j] = f2bf(x[u][j]);
            *(uint4*)&vv[(size_t)(t0 + u) * VALUE_DIM + cc] = *(uint4*)o;
        }
    }
}

// ---------------------------------------------------------------------------
// Gated delta recurrence. grid = (16, 32), block = 256 -> 131072 threads =
// 2 waves/SIMD (TLP hides load latency; the round-4 asm pipeline approach
// was abandoned: delayed-wait asm loads across a loop back-edge race with
// regalloc copies).
// Thread (h, col, kc): kc in [0,32) owns 4 K-rows of state column `col`.
// Algebra: pq = e*dot(S_old,k); dl=(v-pq)*b; S' = S*e + k*dl; o = dot(S',q).
// 32-lane reduce: 4 DPP stages + ds_swizzle xor16. Depth-4 C prefetch.
// ---------------------------------------------------------------------------
__device__ __forceinline__ void recur_step(f32x2 S_[2],
    uint2& rk, uint2& rq, ushort_t& rv, float2& rgb,
    const ushort_t* kp, const ushort_t* qp, const ushort_t* vp,
    const float2* gb, int h, int tpre, float* outp, bool lead)
{
    // consume raw regs first (so prefetch below can overwrite them)
    f32x2 k2[2], q2[2];
    cvt4v2(rk, k2);
    cvt4v2(rq, q2);
    float v_ = bf2f(rv);
    float e = rgb.x, b = rgb.y;
    // prefetch t+4 into the same regs
    rk = *(const uint2*)(kp + (size_t)tpre * KEY_DIM);
    rq = *(const uint2*)(qp + (size_t)tpre * KEY_DIM);
    rv = vp[(size_t)tpre * VALUE_DIM];
    rgb = gb[tpre * HV_ + h];

    // d1 = dot(S_old, k)   (gate scale folded out: pq = e*d1)
    f32x2 acc = S_[0] * k2[0];
    acc += S_[1] * k2[1];
    float d1 = red32(acc.x + acc.y);
    float dl = (v_ - e * d1) * b;
    f32x2 e2  = (f32x2){e, e};
    f32x2 dl2 = (f32x2){dl, dl};
    f32x2 oacc = (f32x2){0.f, 0.f};
#pragma unroll
    for (int j = 0; j < 2; j++) {
        S_[j] = S_[j] * e2 + k2[j] * dl2;   // v_pk_mul + v_pk_fma
        oacc += S_[j] * q2[j];
    }
    float o = red32(oacc.x + oacc.y);
    if (lead) *outp = o;
}

__global__ __launch_bounds__(256) void k_recur(const ushort_t* __restrict__ qn,
                                               const ushort_t* __restrict__ kn,
                                               const ushort_t* __restrict__ vv,
                                               const float2* __restrict__ gb,
                                               float* __restrict__ core)
{
    int h = blockIdx.y;
    int hk = h >> 1;
    int kc = threadIdx.x & 31;          // 32 lanes over DK=128, 4 rows each
    int cl = threadIdx.x >> 5;          // 8 cols per block
    int col = blockIdx.x * 8 + cl;
    int kqoff = hk * 128 + kc * 4;
    bool lead = (kc == 0);

    const ushort_t* kp = kn + kqoff;
    const ushort_t* qp = qn + kqoff;
    const ushort_t* vp = vv + h * 128 + col;
    float* outp = core + h * 128 + col;

    f32x2 S_[2];
#pragma unroll
    for (int j = 0; j < 2; j++) S_[j] = (f32x2){0.f, 0.f};

    // init pipeline: sets A..D <- t = 0..3
    uint2 rka = *(const uint2*)kp;
    uint2 rqa = *(const uint2*)qp;
    ushort_t rva = vp[0];
    float2 gba = gb[h];
    uint2 rkb = *(const uint2*)(kp + KEY_DIM);
    uint2 rqb = *(const uint2*)(qp + KEY_DIM);
    ushort_t rvb = vp[VALUE_DIM];
    float2 gbb = gb[HV_ + h];
    uint2 rkc = *(const uint2*)(kp + 2 * KEY_DIM);
    uint2 rqc = *(const uint2*)(qp + 2 * KEY_DIM);
    ushort_t rvc = vp[2 * VALUE_DIM];
    float2 gbc = gb[2 * HV_ + h];
    uint2 rkd = *(const uint2*)(kp + 3 * KEY_DIM);
    uint2 rqd = *(const uint2*)(qp + 3 * KEY_DIM);
    ushort_t rvd = vp[3 * VALUE_DIM];
    float2 gbd = gb[3 * HV_ + h];

    for (int t = 0; t < SEQ; t += 4) {
        // last iter (t = SEQ-4): re-prefetch t..t+3 (in-range, never consumed)
        int tp = (t <= SEQ - 8) ? (t + 4) : t;
        recur_step(S_, rka, rqa, rva, gba, kp, qp, vp, gb, h, tp,
                   outp + (size_t)t * VALUE_DIM, lead);
        recur_step(S_, rkb, rqb, rvb, gbb, kp, qp, vp, gb, h, tp + 1,
                   outp + (size_t)(t + 1) * VALUE_DIM, lead);
        recur_step(S_, rkc, rqc, rvc, gbc, kp, qp, vp, gb, h, tp + 2,
                   outp + (size_t)(t + 2) * VALUE_DIM, lead);
        recur_step(S_, rkd, rqd, rvd, gbd, kp, qp, vp, gb, h, tp + 3,
                   outp + (size_t)(t + 3) * VALUE_DIM, lead);
    }
}

// ---------------------------------------------------------------------------
// RMS norm + gate; emits bf16 core for the MFMA out-GEMM. grid (32,4096).
// ---------------------------------------------------------------------------
__global__ void k_gate(const float* __restrict__ core, const ushort_t* __restrict__ z,
                       const float* __restrict__ nw, ushort_t* __restrict__ corebf)
{
    __shared__ float red[2];
    int hv = blockIdx.x, t = blockIdx.y, d = threadIdx.x;
    size_t idx = (size_t)t * VALUE_DIM + hv * 128 + d;
    float cval = core[idx];
    float ss = cval * cval;
    for (int m = 32; m >= 1; m >>= 1) ss += __shfl_xor(ss, m, 64);
    int wv = d >> 6, ln = d & 63;
    if (ln == 0) red[wv] = ss;
    __syncthreads();
    float var = (red[0] + red[1]) * (1.f / 128.f);
    float zv = bf2f(z[idx]);
    float out = cval * (1.f / sqrtf(var + 1e-6f)) * nw[d] * (zv / (1.f + expf(-zv)));
    corebf[idx] = f2bf(out);
}

// ---------------------------------------------------------------------------
// Workspace (161 MB):
//   P [0,64M):   preact bf16 -> core f32 (after conv)
//   Z [64,96M):  z bf16
//   gb (1 MB float2: exp(g), beta interleaved)
//   QKV [97,161M): qn/kn/vv bf16 (64 MB contiguous)
// Aliases by lifetime:
//   before conv: QKV holds WqkvzT bf16 (48 MB) + hs bf16 (16 MB)
//   after recur: vv holds WoutT bf16 (16 MB); qn+kn hold core_bf16 (32 MB)
// ---------------------------------------------------------------------------
extern "C" void kernel_launch(void* const* d_in, const int* in_sizes, int n_in,
                              void* d_out, int out_size, void* d_ws, size_t ws_size,
                              hipStream_t stream)
{
    const float* hs    = (const float*)d_in[0];
    const float* Wqkvz = (const float*)d_in[1];
    const float* Wba   = (const float*)d_in[2];
    const float* convw = (const float*)d_in[3];
    const float* Alog  = (const float*)d_in[4];
    const float* dtb   = (const float*)d_in[5];
    const float* nw    = (const float*)d_in[6];
    const float* Wout  = (const float*)d_in[7];
    float* out = (float*)d_out;

    char* w = (char*)d_ws;
    ushort_t* preact = (ushort_t*)w;            // 64 MB (bf16)
    float*    coreb  = (float*)w;               // aliases preact (dead after k_conv)
    w += (size_t)SEQ * CONV_DIM * 2;
    ushort_t* zb = (ushort_t*)w;  w += (size_t)SEQ * VALUE_DIM * 2;
    float* gbf   = (float*)w;     w += (size_t)SEQ * HV_ * 8;   // float2 interleaved
    ushort_t* qnb = (ushort_t*)w; w += (size_t)SEQ * KEY_DIM * 2;
    ushort_t* knb = (ushort_t*)w; w += (size_t)SEQ * KEY_DIM * 2;
    ushort_t* vvb = (ushort_t*)w; w += (size_t)SEQ * VALUE_DIM * 2;
    size_t needed = (size_t)(w - (char*)d_ws);
    if (ws_size < needed) return;

    // lifetime aliases
    ushort_t* wqT    = qnb;                               // 48 MB: [12288][2048] bf16
    ushort_t* hsb    = qnb + (size_t)24 * 1024 * 1024;    // 16 MB: [4096][2048] bf16
    ushort_t* woutT  = vvb;                               // 16 MB: [2048][4096] bf16
    ushort_t* corebf = qnb;                               // 32 MB: [4096][4096] bf16

    hipLaunchKernelGGL(k_ba, dim3(32), dim3(256), 0, stream, hs, Wba, Alog, dtb, gbf);
    hipLaunchKernelGGL(k_cvt, dim3(4096), dim3(256), 0, stream, hs, hsb);
    hipLaunchKernelGGL(k_transpose, dim3(192, 32), dim3(256), 0, stream, Wqkvz, wqT, HID, NQKVZ);
    hipLaunchKernelGGL(k_gemm_qkvz, dim3(96, 32), dim3(256), 0, stream, hsb, wqT, preact, zb);
    hipLaunchKernelGGL(k_conv, dim3(4, 1024), dim3(256), 0, stream, preact, convw, qnb, knb, vvb);
    hipLaunchKernelGGL(k_recur, dim3(16, 32), dim3(256), 0, stream, qnb, knb, vvb,
                       (const float2*)gbf, coreb);
    hipLaunchKernelGGL(k_transpose, dim3(32, 64), dim3(256), 0, stream, Wout, woutT, VALUE_DIM, HID);
    hipLaunchKernelGGL(k_gate, dim3(32, 4096), dim3(128), 0, stream, coreb, zb, nw, corebf);
    hipLaunchKernelGGL(k_gemm_out, dim3(16, 32), dim3(256), 0, stream, corebf, woutT, out);
}

// Round 7
// 1560.525 us; speedup vs baseline: 1.5631x; 1.5631x over previous
//
#include <hip/hip_runtime.h>
#include <hip/hip_bf16.h>

#define SEQ 4096
#define HID 2048
#define HK_ 16
#define HV_ 32
#define KEY_DIM 2048
#define VALUE_DIM 4096
#define CONV_DIM 8192
#define NQKVZ 12288

typedef unsigned short ushort_t;
typedef short bf16x8 __attribute__((ext_vector_type(8)));
typedef float f32x4 __attribute__((ext_vector_type(4)));
typedef float f32x2 __attribute__((ext_vector_type(2)));

__device__ __forceinline__ float bf2f(ushort_t h) {
    union { unsigned int u; float f; } x; x.u = ((unsigned int)h) << 16; return x.f;
}
__device__ __forceinline__ void cvt8(uint4 v, float* f) {
    unsigned int w[4] = {v.x, v.y, v.z, v.w};
#pragma unroll
    for (int i = 0; i < 4; i++) {
        union { unsigned int u; float f; } lo, hi;
        lo.u = w[i] << 16; hi.u = w[i] & 0xffff0000u;
        f[2 * i] = lo.f; f[2 * i + 1] = hi.f;
    }
}
// bf16x8 word -> 4x f32x2 (lo,hi pairs), packed-math friendly
__device__ __forceinline__ void cvt8v(uint4 v, f32x2* f) {
    unsigned int w[4] = {v.x, v.y, v.z, v.w};
#pragma unroll
    for (int i = 0; i < 4; i++) {
        union { unsigned int u; float f; } lo, hi;
        lo.u = w[i] << 16; hi.u = w[i] & 0xffff0000u;
        f[i] = (f32x2){lo.f, hi.f};
    }
}
__device__ __forceinline__ ushort_t f2bf(float f) {
    union { float f; unsigned int u; } x; x.f = f;
    unsigned int u = x.u;
    u += 0x7fffu + ((u >> 16) & 1u);   // round-to-nearest-even
    return (ushort_t)(u >> 16);
}

// async global->LDS. LDS dest is wave-uniform base; HW writes base + lane*width.
__device__ __forceinline__ void gload_lds16(const void* g, void* l) {
    __builtin_amdgcn_global_load_lds(
        (const __attribute__((address_space(1))) void*)g,
        (__attribute__((address_space(3))) void*)l, 16, 0, 0);
}
__device__ __forceinline__ void gload_lds4(const void* g, void* l) {
    __builtin_amdgcn_global_load_lds(
        (const __attribute__((address_space(1))) void*)g,
        (__attribute__((address_space(3))) void*)l, 4, 0, 0);
}

// DPP butterfly add within a 16-lane row (VALU-latency cross-lane).
template <int CTRL>
__device__ __forceinline__ float dpp_add(float x) {
    union { float f; int i; } a, b;
    a.f = x;
    b.i = __builtin_amdgcn_update_dpp(0, a.i, CTRL, 0xF, 0xF, true);
    return a.f + b.f;
}
// full 16-lane sum, result in all 16 lanes of the row
__device__ __forceinline__ float red16(float x) {
    x = dpp_add<0xB1>(x);   // quad_perm [1,0,3,2]  : xor 1
    x = dpp_add<0x4E>(x);   // quad_perm [2,3,0,1]  : xor 2
    x = dpp_add<0x141>(x);  // row_half_mirror      : xor 4
    x = dpp_add<0x140>(x);  // row_mirror           : xor 8
    return x;
}

// ---------------------------------------------------------------------------
// f32 -> bf16 flat copy (n divisible by 2048). 8 elems/thread.
// ---------------------------------------------------------------------------
__global__ void k_cvt(const float* __restrict__ src, ushort_t* __restrict__ dst)
{
    size_t i = ((size_t)blockIdx.x * 256 + threadIdx.x) * 8;
    float4 a = *(const float4*)&src[i];
    float4 b = *(const float4*)&src[i + 4];
    ushort_t u[8];
    u[0]=f2bf(a.x); u[1]=f2bf(a.y); u[2]=f2bf(a.z); u[3]=f2bf(a.w);
    u[4]=f2bf(b.x); u[5]=f2bf(b.y); u[6]=f2bf(b.z); u[7]=f2bf(b.w);
    *(uint4*)&dst[i] = *(uint4*)u;
}

// ---------------------------------------------------------------------------
// Transpose f32 [R][C] -> bf16 [C][R]. 64x64 tiles via LDS. grid (C/64, R/64).
// ---------------------------------------------------------------------------
__global__ __launch_bounds__(256) void k_transpose(const float* __restrict__ src,
                                                   ushort_t* __restrict__ dst,
                                                   int R, int C)
{
    __shared__ float tile[64][65];
    int c0 = blockIdx.x * 64, r0 = blockIdx.y * 64;
    int t = threadIdx.x;
    int tr = t >> 4, tc = (t & 15) * 4;
#pragma unroll
    for (int r = 0; r < 4; r++) {
        float4 v = *(const float4*)&src[(size_t)(r0 + tr + r * 16) * C + c0 + tc];
        tile[tr + r * 16][tc + 0] = v.x;
        tile[tr + r * 16][tc + 1] = v.y;
        tile[tr + r * 16][tc + 2] = v.z;
        tile[tr + r * 16][tc + 3] = v.w;
    }
    __syncthreads();
#pragma unroll
    for (int r = 0; r < 4; r++) {
        int n = c0 + tr + r * 16;           // dst row (src col)
        ushort_t u[4];
#pragma unroll
        for (int i = 0; i < 4; i++) u[i] = f2bf(tile[tc + i][tr + r * 16]);
        *(uint2*)&dst[(size_t)n * R + r0 + tc] = *(uint2*)u;
    }
}

// ---------------------------------------------------------------------------
// ba = hidden @ W_ba (2048x64), f32 in, fused g/beta transform.
// Writes interleaved float2 gb[t*HV_+hv] = (exp(g), beta).
// ---------------------------------------------------------------------------
__global__ void k_ba(const float* __restrict__ A, const float* __restrict__ B,
                     const float* __restrict__ A_log, const float* __restrict__ dt_bias,
                     float* __restrict__ gbf)
{
    __shared__ float As[16][132];
    __shared__ float Bs[16][68];
    int tid = threadIdx.x;
    int m0 = blockIdx.x * 128;
    int tx = tid & 15, ty = tid >> 4;
    int arow = tid >> 2, akq = tid & 3;
    int brow = tid >> 4, bc4 = tid & 15;
    float acc[8][4];
#pragma unroll
    for (int i = 0; i < 8; i++)
#pragma unroll
        for (int j = 0; j < 4; j++) acc[i][j] = 0.f;

    for (int k0 = 0; k0 < HID; k0 += 16) {
        float4 a0 = *(const float4*)&A[(size_t)(m0 + arow) * HID + k0 + akq * 4];
        float4 a1 = *(const float4*)&A[(size_t)(m0 + arow + 64) * HID + k0 + akq * 4];
        float4 b0 = *(const float4*)&B[(size_t)(k0 + brow) * 64 + bc4 * 4];
        __syncthreads();
        As[akq * 4 + 0][arow] = a0.x; As[akq * 4 + 1][arow] = a0.y;
        As[akq * 4 + 2][arow] = a0.z; As[akq * 4 + 3][arow] = a0.w;
        As[akq * 4 + 0][arow + 64] = a1.x; As[akq * 4 + 1][arow + 64] = a1.y;
        As[akq * 4 + 2][arow + 64] = a1.z; As[akq * 4 + 3][arow + 64] = a1.w;
        *(float4*)&Bs[brow][bc4 * 4] = b0;
        __syncthreads();
#pragma unroll
        for (int kk = 0; kk < 16; kk++) {
            float xa[8], yb[4];
            *(float4*)&xa[0] = *(const float4*)&As[kk][ty * 8];
            *(float4*)&xa[4] = *(const float4*)&As[kk][ty * 8 + 4];
            *(float4*)&yb[0] = *(const float4*)&Bs[kk][tx * 4];
#pragma unroll
            for (int i = 0; i < 8; i++)
#pragma unroll
                for (int j = 0; j < 4; j++) acc[i][j] += xa[i] * yb[j];
        }
    }
#pragma unroll
    for (int i = 0; i < 8; i++) {
        int t = m0 + ty * 8 + i;
#pragma unroll
        for (int j = 0; j < 4; j++) {
            int c = tx * 4 + j;
            int hk = c >> 2, rr = c & 3;
            float val = acc[i][j];
            if (rr < 2) {
                int hv = hk * 2 + rr;
                gbf[(t * HV_ + hv) * 2 + 1] = 1.f / (1.f + expf(-val));
            } else {
                int hv = hk * 2 + (rr - 2);
                float v2 = val + dt_bias[hv];
                float sp = (v2 > 20.f) ? v2 : log1pf(expf(v2));
                float g = -expf(A_log[hv]) * sp;
                gbf[(t * HV_ + hv) * 2 + 0] = expf(g);
            }
        }
    }
}

// ---------------------------------------------------------------------------
// MFMA GEMM (m97 structure): global_load_lds width-16 staging, linear LDS.
// qkvz = hs_bf16 [4096][2048] @ WqkvzT_bf16 [12288][2048]^T. grid (96, 32).
// ---------------------------------------------------------------------------
__global__ __launch_bounds__(256) void k_gemm_qkvz(const ushort_t* __restrict__ Ab,
                                                   const ushort_t* __restrict__ Bt,
                                                   ushort_t* __restrict__ preact,
                                                   ushort_t* __restrict__ zb)
{
    __shared__ ushort_t As[128][32];
    __shared__ ushort_t Bs[128][32];
    int tid = threadIdx.x;
    int m0 = blockIdx.y * 128, n0 = blockIdx.x * 128;
    int lane = tid & 63, wave = tid >> 6;
    int wm = (wave >> 1) * 64, wn = (wave & 1) * 64;
    int quad = lane >> 4, l16 = lane & 15;

    int srow = ((wave & 1) << 6) + (lane >> 2);
    int scol = (lane & 3) << 3;
    const ushort_t* gsrc = (wave < 2)
        ? &Ab[(size_t)(m0 + srow) * HID + scol]
        : &Bt[(size_t)(n0 + srow) * HID + scol];
    ushort_t* lbase = ((wave < 2) ? &As[0][0] : &Bs[0][0]) + ((wave & 1) << 11);

    f32x4 acc[4][4];
#pragma unroll
    for (int i = 0; i < 4; i++)
#pragma unroll
        for (int j = 0; j < 4; j++) acc[i][j] = (f32x4){0.f, 0.f, 0.f, 0.f};

    for (int k0 = 0; k0 < HID; k0 += 32) {
#pragma unroll
        for (int i = 0; i < 4; i++)
            gload_lds16(gsrc + k0 + (size_t)i * 16 * HID, lbase + i * 512);
        __syncthreads();
        bf16x8 af[4], bfr[4];
#pragma unroll
        for (int i = 0; i < 4; i++) af[i]  = *(bf16x8*)&As[wm + i * 16 + l16][quad * 8];
#pragma unroll
        for (int j = 0; j < 4; j++) bfr[j] = *(bf16x8*)&Bs[wn + j * 16 + l16][quad * 8];
#pragma unroll
        for (int i = 0; i < 4; i++)
#pragma unroll
            for (int j = 0; j < 4; j++)
                acc[i][j] = __builtin_amdgcn_mfma_f32_16x16x32_bf16(af[i], bfr[j], acc[i][j], 0, 0, 0);
        __syncthreads();
    }
    int hk = n0 / 768, r = n0 % 768;
    ushort_t* dst; int ldd;
    if (r < 128)      { dst = preact + hk * 128;                    ldd = CONV_DIM; }
    else if (r < 256) { dst = preact + 2048 + hk * 128;             ldd = CONV_DIM; }
    else if (r < 512) { dst = preact + 4096 + hk * 256 + (r - 256); ldd = CONV_DIM; }
    else              { dst = zb + hk * 256 + (r - 512);            ldd = VALUE_DIM; }
#pragma unroll
    for (int i = 0; i < 4; i++)
#pragma unroll
        for (int j = 0; j < 4; j++)
#pragma unroll
            for (int rg = 0; rg < 4; rg++) {
                int m = m0 + wm + i * 16 + quad * 4 + rg;
                int n = wn + j * 16 + l16;
                dst[(size_t)m * ldd + n] = f2bf(acc[i][j][rg]);
            }
}

// ---------------------------------------------------------------------------
// MFMA GEMM (m97 structure): out = core_bf16 [4096][4096] @ WoutT [2048][4096]^T.
// grid (16, 32).
// ---------------------------------------------------------------------------
__global__ __launch_bounds__(256) void k_gemm_out(const ushort_t* __restrict__ Ab,
                                                  const ushort_t* __restrict__ Bt,
                                                  float* __restrict__ C)
{
    __shared__ ushort_t As[128][32];
    __shared__ ushort_t Bs[128][32];
    int tid = threadIdx.x;
    int m0 = blockIdx.y * 128, n0 = blockIdx.x * 128;
    int lane = tid & 63, wave = tid >> 6;
    int wm = (wave >> 1) * 64, wn = (wave & 1) * 64;
    int quad = lane >> 4, l16 = lane & 15;

    int srow = ((wave & 1) << 6) + (lane >> 2);
    int scol = (lane & 3) << 3;
    const ushort_t* gsrc = (wave < 2)
        ? &Ab[(size_t)(m0 + srow) * VALUE_DIM + scol]
        : &Bt[(size_t)(n0 + srow) * VALUE_DIM + scol];
    ushort_t* lbase = ((wave < 2) ? &As[0][0] : &Bs[0][0]) + ((wave & 1) << 11);

    f32x4 acc[4][4];
#pragma unroll
    for (int i = 0; i < 4; i++)
#pragma unroll
        for (int j = 0; j < 4; j++) acc[i][j] = (f32x4){0.f, 0.f, 0.f, 0.f};

    for (int k0 = 0; k0 < VALUE_DIM; k0 += 32) {
#pragma unroll
        for (int i = 0; i < 4; i++)
            gload_lds16(gsrc + k0 + (size_t)i * 16 * VALUE_DIM, lbase + i * 512);
        __syncthreads();
        bf16x8 af[4], bfr[4];
#pragma unroll
        for (int i = 0; i < 4; i++) af[i]  = *(bf16x8*)&As[wm + i * 16 + l16][quad * 8];
#pragma unroll
        for (int j = 0; j < 4; j++) bfr[j] = *(bf16x8*)&Bs[wn + j * 16 + l16][quad * 8];
#pragma unroll
        for (int i = 0; i < 4; i++)
#pragma unroll
            for (int j = 0; j < 4; j++)
                acc[i][j] = __builtin_amdgcn_mfma_f32_16x16x32_bf16(af[i], bfr[j], acc[i][j], 0, 0, 0);
        __syncthreads();
    }
#pragma unroll
    for (int i = 0; i < 4; i++)
#pragma unroll
        for (int j = 0; j < 4; j++)
#pragma unroll
            for (int rg = 0; rg < 4; rg++) {
                int m = m0 + wm + i * 16 + quad * 4 + rg;
                int n = n0 + wn + j * 16 + l16;
                C[(size_t)m * HID + n] = acc[i][j][rg];
            }
}

// ---------------------------------------------------------------------------
// Causal conv(K=4) + SiLU; l2norm for q/k heads. Vectorized: 8 ch/thread.
// grid (4, SEQ/4), block 256. block.x 0: q, 1: k, 2-3: v.
// ---------------------------------------------------------------------------
__global__ __launch_bounds__(256) void k_conv(const ushort_t* __restrict__ pre,
                                              const float* __restrict__ cw,
                                              ushort_t* __restrict__ qn,
                                              ushort_t* __restrict__ kn,
                                              ushort_t* __restrict__ vv)
{
    int tid = threadIdx.x;
    int c = blockIdx.x * 2048 + tid * 8;
    int t0 = blockIdx.y * 4;
    float w[8][4];
#pragma unroll
    for (int j = 0; j < 8; j++)
        *(float4*)w[j] = *(const float4*)&cw[(size_t)(c + j) * 4];
    float p[7][8];
#pragma unroll
    for (int i = 0; i < 7; i++) {
        int tt = t0 + i - 3;
        if (tt >= 0) {
            uint4 v = *(const uint4*)&pre[(size_t)tt * CONV_DIM + c];
            cvt8(v, p[i]);
        } else {
#pragma unroll
            for (int j = 0; j < 8; j++) p[i][j] = 0.f;
        }
    }
    float x[4][8];
#pragma unroll
    for (int u = 0; u < 4; u++)
#pragma unroll
        for (int j = 0; j < 8; j++) {
            float a = p[u][j] * w[j][0] + p[u + 1][j] * w[j][1]
                    + p[u + 2][j] * w[j][2] + p[u + 3][j] * w[j][3];
            x[u][j] = a / (1.f + expf(-a));
        }
    if (blockIdx.x < 2) {
        bool isq = (blockIdx.x == 0);
        float headscale = isq ? 0.08838834764831845f : 1.f;
        ushort_t* dst = isq ? qn : kn;
        int cc = isq ? c : (c - KEY_DIM);
#pragma unroll
        for (int u = 0; u < 4; u++) {
            float ss = 0.f;
#pragma unroll
            for (int j = 0; j < 8; j++) ss += x[u][j] * x[u][j];
            ss = red16(ss);                      // head = 128 ch = 16 lanes
            float mul = headscale / sqrtf(ss + 1e-6f);
            ushort_t o[8];
#pragma unroll
            for (int j = 0; j < 8; j++) o[j] = f2bf(x[u][j] * mul);
            *(uint4*)&dst[(size_t)(t0 + u) * KEY_DIM + cc] = *(uint4*)o;
        }
    } else {
        int cc = c - 2 * KEY_DIM;
#pragma unroll
        for (int u = 0; u < 4; u++) {
            ushort_t o[8];
#pragma unroll
            for (int j = 0; j < 8; j++) o[j] = f2bf(x[u][j]);
            *(uint4*)&vv[(size_t)(t0 + u) * VALUE_DIM + cc] = *(uint4*)o;
        }
    }
}

// ---------------------------------------------------------------------------
// Gated delta recurrence. grid = (8, 32), block = 256.
// Thread (h, col, kc): kc in [0,16) owns 8 K-rows of state column `col`.
// Algebra: pq = e*dot(S_old,k); dl=(v-pq)*b; S' = S*e + k*dl; o = dot(S',q).
//
// Latency fix (r6 post-mortem): register prefetch gets sunk by the compiler
// (VGPR=36) and asm pipelines across a back-edge are regalloc-unsafe (r5).
// Instead: chunk-level LDS double-buffer via global_load_lds (the proven m97
// mechanism). Stage 32 timesteps of k/q/v/gb (17.25KB) into buf B while
// computing from buf A; one __syncthreads per chunk (drains vmcnt). Staging
// has ~6400cy of compute to hide under (~900cy needed). Per-step ds_reads
// are hoistable by the compiler (fine-grained lgkmcnt, m97 asm evidence).
// Also removes the 16x redundant per-group k/q global reads.
// ---------------------------------------------------------------------------
__global__ __launch_bounds__(256) void k_recur(const ushort_t* __restrict__ qn,
                                               const ushort_t* __restrict__ kn,
                                               const ushort_t* __restrict__ vv,
                                               const float2* __restrict__ gb,
                                               float* __restrict__ core)
{
    __shared__ ushort_t Ks[2][32][128];   // 8KB each buf
    __shared__ ushort_t Qs[2][32][128];   // 8KB
    __shared__ ushort_t Vs[2][32][16];    // 1KB
    __shared__ float    Gs[2][32][2];     // 256B
    int tid = threadIdx.x;
    int h = blockIdx.y;
    int hk = h >> 1;
    int kc = tid & 15;
    int cl = tid >> 4;
    bool lead = (kc == 0);
    int lane = tid & 63, wave = tid >> 6;

    const ushort_t* kh = kn + hk * 128;
    const ushort_t* qh = qn + hk * 128;
    const ushort_t* vh = vv + h * 128 + blockIdx.x * 16;
    const float*    gh = (const float*)(gb + h);
    float* outp = core + h * 128 + blockIdx.x * 16 + cl;

    // stage chunk [t0, t0+32) into buffer bi.
    // k/q: lane l -> row rb+c*4+(l>>4), bytes (l&15)*16 ; LDS dst base+l*16. ✓
    // v:   lane l -> row rb+c*8+(l>>3), bytes (l&7)*4   ; dst base+l*4. ✓
    // gb:  lane l -> row l>>1, float l&1                ; dst base+l*4. ✓
    auto stage = [&](int bi, int t0) {
        if (wave < 2) {
            int rb = wave * 16;
#pragma unroll
            for (int c = 0; c < 4; c++) {
                int r = rb + c * 4 + (lane >> 4);
                gload_lds16(kh + (size_t)(t0 + r) * KEY_DIM + (lane & 15) * 8,
                            &Ks[bi][rb + c * 4][0]);
            }
#pragma unroll
            for (int c = 0; c < 2; c++) {
                int r = rb + c * 8 + (lane >> 3);
                gload_lds4(vh + (size_t)(t0 + r) * VALUE_DIM + (lane & 7) * 2,
                           &Vs[bi][rb + c * 8][0]);
            }
        } else {
            int rb = (wave - 2) * 16;
#pragma unroll
            for (int c = 0; c < 4; c++) {
                int r = rb + c * 4 + (lane >> 4);
                gload_lds16(qh + (size_t)(t0 + r) * KEY_DIM + (lane & 15) * 8,
                            &Qs[bi][rb + c * 4][0]);
            }
            if (wave == 2) {
                int r = lane >> 1;
                gload_lds4(gh + (size_t)(t0 + r) * (HV_ * 2) + (lane & 1),
                           &Gs[bi][0][0]);
            }
        }
    };

    f32x2 S_[4];
#pragma unroll
    for (int j = 0; j < 4; j++) S_[j] = (f32x2){0.f, 0.f};

    stage(0, 0);
    __syncthreads();   // drains vmcnt before barrier (compiler-guaranteed)

    for (int tc = 0; tc < SEQ / 32; tc++) {
        int bi = tc & 1;
        if (tc + 1 < SEQ / 32) stage(bi ^ 1, (tc + 1) * 32);  // async prefetch
        int t0 = tc * 32;
#pragma unroll 8
        for (int s = 0; s < 32; s++) {
            uint4 kvr = *(const uint4*)&Ks[bi][s][kc * 8];
            uint4 qvr = *(const uint4*)&Qs[bi][s][kc * 8];
            f32x2 k2[4], q2[4];
            cvt8v(kvr, k2);
            cvt8v(qvr, q2);
            float v_ = bf2f(Vs[bi][s][cl]);
            float e = Gs[bi][s][0], b = Gs[bi][s][1];
            // d1 = dot(S_old, k); pq = e*d1 (gate folded out of the dot)
            f32x2 acc = S_[0] * k2[0];
            acc += S_[1] * k2[1];
            acc += S_[2] * k2[2];
            acc += S_[3] * k2[3];
            float d1 = red16(acc.x + acc.y);
            float dl = (v_ - e * d1) * b;
            f32x2 e2 = (f32x2){e, e}, dl2 = (f32x2){dl, dl};
            f32x2 oacc = (f32x2){0.f, 0.f};
#pragma unroll
            for (int j = 0; j < 4; j++) {
                S_[j] = S_[j] * e2 + k2[j] * dl2;   // v_pk_mul + v_pk_fma
                oacc += S_[j] * q2[j];
            }
            float o = red16(oacc.x + oacc.y);
            if (lead) outp[(size_t)(t0 + s) * VALUE_DIM] = o;
        }
        __syncthreads();   // all reads of bi done + next-chunk staging landed
    }
}

// ---------------------------------------------------------------------------
// RMS norm + gate; emits bf16 core for the MFMA out-GEMM. grid (32,4096).
// ---------------------------------------------------------------------------
__global__ void k_gate(const float* __restrict__ core, const ushort_t* __restrict__ z,
                       const float* __restrict__ nw, ushort_t* __restrict__ corebf)
{
    __shared__ float red[2];
    int hv = blockIdx.x, t = blockIdx.y, d = threadIdx.x;
    size_t idx = (size_t)t * VALUE_DIM + hv * 128 + d;
    float cval = core[idx];
    float ss = cval * cval;
    for (int m = 32; m >= 1; m >>= 1) ss += __shfl_xor(ss, m, 64);
    int wv = d >> 6, ln = d & 63;
    if (ln == 0) red[wv] = ss;
    __syncthreads();
    float var = (red[0] + red[1]) * (1.f / 128.f);
    float zv = bf2f(z[idx]);
    float out = cval * (1.f / sqrtf(var + 1e-6f)) * nw[d] * (zv / (1.f + expf(-zv)));
    corebf[idx] = f2bf(out);
}

// ---------------------------------------------------------------------------
// Workspace (161 MB):
//   P [0,64M):   preact bf16 -> core f32 (after conv)
//   Z [64,96M):  z bf16
//   gb (1 MB float2: exp(g), beta interleaved)
//   QKV [97,161M): qn/kn/vv bf16 (64 MB contiguous)
// Aliases by lifetime:
//   before conv: QKV holds WqkvzT bf16 (48 MB) + hs bf16 (16 MB)
//   after recur: vv holds WoutT bf16 (16 MB); qn+kn hold core_bf16 (32 MB)
// ---------------------------------------------------------------------------
extern "C" void kernel_launch(void* const* d_in, const int* in_sizes, int n_in,
                              void* d_out, int out_size, void* d_ws, size_t ws_size,
                              hipStream_t stream)
{
    const float* hs    = (const float*)d_in[0];
    const float* Wqkvz = (const float*)d_in[1];
    const float* Wba   = (const float*)d_in[2];
    const float* convw = (const float*)d_in[3];
    const float* Alog  = (const float*)d_in[4];
    const float* dtb   = (const float*)d_in[5];
    const float* nw    = (const float*)d_in[6];
    const float* Wout  = (const float*)d_in[7];
    float* out = (float*)d_out;

    char* w = (char*)d_ws;
    ushort_t* preact = (ushort_t*)w;            // 64 MB (bf16)
    float*    coreb  = (float*)w;               // aliases preact (dead after k_conv)
    w += (size_t)SEQ * CONV_DIM * 2;
    ushort_t* zb = (ushort_t*)w;  w += (size_t)SEQ * VALUE_DIM * 2;
    float* gbf   = (float*)w;     w += (size_t)SEQ * HV_ * 8;   // float2 interleaved
    ushort_t* qnb = (ushort_t*)w; w += (size_t)SEQ * KEY_DIM * 2;
    ushort_t* knb = (ushort_t*)w; w += (size_t)SEQ * KEY_DIM * 2;
    ushort_t* vvb = (ushort_t*)w; w += (size_t)SEQ * VALUE_DIM * 2;
    size_t needed = (size_t)(w - (char*)d_ws);
    if (ws_size < needed) return;

    // lifetime aliases
    ushort_t* wqT    = qnb;                               // 48 MB: [12288][2048] bf16
    ushort_t* hsb    = qnb + (size_t)24 * 1024 * 1024;    // 16 MB: [4096][2048] bf16
    ushort_t* woutT  = vvb;                               // 16 MB: [2048][4096] bf16
    ushort_t* corebf = qnb;                               // 32 MB: [4096][4096] bf16

    hipLaunchKernelGGL(k_ba, dim3(32), dim3(256), 0, stream, hs, Wba, Alog, dtb, gbf);
    hipLaunchKernelGGL(k_cvt, dim3(4096), dim3(256), 0, stream, hs, hsb);
    hipLaunchKernelGGL(k_transpose, dim3(192, 32), dim3(256), 0, stream, Wqkvz, wqT, HID, NQKVZ);
    hipLaunchKernelGGL(k_gemm_qkvz, dim3(96, 32), dim3(256), 0, stream, hsb, wqT, preact, zb);
    hipLaunchKernelGGL(k_conv, dim3(4, 1024), dim3(256), 0, stream, preact, convw, qnb, knb, vvb);
    hipLaunchKernelGGL(k_recur, dim3(8, 32), dim3(256), 0, stream, qnb, knb, vvb,
                       (const float2*)gbf, coreb);
    hipLaunchKernelGGL(k_transpose, dim3(32, 64), dim3(256), 0, stream, Wout, woutT, VALUE_DIM, HID);
    hipLaunchKernelGGL(k_gate, dim3(32, 4096), dim3(128), 0, stream, coreb, zb, nw, corebf);
    hipLaunchKernelGGL(k_gemm_out, dim3(16, 32), dim3(256), 0, stream, corebf, woutT, out);
}